// Round 1
// 928.967 us; speedup vs baseline: 1.1854x; 1.1854x over previous
//
#include <hip/hip_runtime.h>
#include <hip/hip_bf16.h>
#include <math.h>

#define BQ 32
#define SQ 197
#define EQ 768
#define HQ 12
#define DHQ 64
#define FQ 2048
#define LQ 4
#define CQ 1000
#define BSQ (BQ*SQ)     // 6304
#define SP 208          // padded rows per batch (13 * 16)
#define S16 13          // 16-row tiles per batch
#define MP (BQ*SP)      // 6656 padded total rows
#define QKV3 2304
#define KTP 7           // t-chunks of 32 (224) for P / V
#define LN_EPS 1e-5f

typedef __bf16 bf16x8 __attribute__((ext_vector_type(8)));
typedef float f32x4 __attribute__((ext_vector_type(4)));
typedef unsigned short u16x8 __attribute__((ext_vector_type(8)));

typedef const __attribute__((address_space(1))) unsigned int* gas_t;
typedef __attribute__((address_space(3))) unsigned int* las_t;

__device__ __forceinline__ __hip_bfloat16 tobf(float f) { return __float2bfloat16(f); }

// Packed fragment layout: chunk of 8 bf16 for (row-tile rt, k-tile kt, lane):
//   buf[pk(rt,KT,kt,lane)+e] <-> A[rt*16+(lane&15)][kt*32+(lane>>4)*8+e]
__device__ __forceinline__ size_t pk(int rt, int KT, int kt, int lane) {
    return (((size_t)rt * KT + kt) * 64 + (size_t)lane) * 8;
}

// sizes (elems)
#define QPK_SLAB (S16*2*512)            // per (b,h): 13 rt x 2 kt x 512
#define QPK_TOT  ((size_t)BQ*HQ*QPK_SLAB + 4096)
#define VPK_SLAB (4*KTP*512)            // per (b,h): 4 dt x 7 tt x 512
#define VPK_TOT  ((size_t)BQ*HQ*VPK_SLAB + 4096)

template<int N>
__device__ __forceinline__ void waitvm() {
    asm volatile("s_waitcnt vmcnt(%0)" :: "n"(N) : "memory");
}
__device__ __forceinline__ void barx() {
    asm volatile("" ::: "memory");
    __builtin_amdgcn_s_barrier();
    asm volatile("" ::: "memory");
}

// fast exact-form GELU: erf via A&S 7.1.26 (|erf err| < 1.5e-7) — replaces
// divergent libm erff in the FF1 epilogue.
__device__ __forceinline__ float gelu_f(float v) {
    float ax = fabsf(v) * 0.70710678118654752f;
    float t  = __builtin_amdgcn_rcpf(1.0f + 0.3275911f * ax);
    float p  = ((((1.061405429f * t - 1.453152027f) * t + 1.421413741f) * t
               - 0.284496736f) * t + 0.254829592f) * t;
    float e  = __expf(-ax * ax);
    float er = 1.0f - p * e;                 // erf(|x|)
    return v * (0.5f * (1.0f + copysignf(er, v)));
}

// ---------------- copy x into padded residual stream ------------------------
__global__ __launch_bounds__(256) void copy_pad(const float* __restrict__ x,
    float* __restrict__ bh)
{
    int r = blockIdx.x;
    int b = r / SQ, s = r % SQ;
    const float* src = x + (size_t)r * EQ;
    float* dst = bh + ((size_t)b * SP + s) * EQ;
    int t = threadIdx.x;
    dst[t] = src[t];
    dst[t + 256] = src[t + 256];
    dst[t + 512] = src[t + 512];
}

// ---------------- transpose + convert + PACK weights ------------------------
__device__ __forceinline__ void tconv_body(const float* __restrict__ ip,
    unsigned short* __restrict__ out, int C, int KT, int ntb_base, int r0, int c0)
{
    __shared__ float tile[64][65];
    int t = threadIdx.x;
    int tc = t & 63, tr = t >> 6;
    #pragma unroll
    for (int p = 0; p < 16; ++p) {
        int r = p * 4 + tr;
        tile[r][tc] = ip[(size_t)(r0 + r) * C + c0 + tc];
    }
    __syncthreads();
    int ntb = ntb_base + (c0 >> 4);
    int ktb = r0 >> 5;
    #pragma unroll
    for (int p = 0; p < 2; ++p) {
        int cc = p * 256 + t;
        int lane = cc & 63, grp = cc >> 6;
        int ktl = grp & 1, ntl = grp >> 1;
        int er = ktl * 32 + (lane >> 4) * 8;
        int dc = ntl * 16 + (lane & 15);
        u16x8 v;
        #pragma unroll
        for (int e = 0; e < 8; ++e) {
            __hip_bfloat16 h = tobf(tile[er + e][dc]);
            v[e] = *(unsigned short*)&h;
        }
        *(u16x8*)(out + pk(ntb + ntl, KT, ktb + ktl, lane)) = v;
    }
}

__global__ __launch_bounds__(256) void tconv_pk(const float* __restrict__ in,
    unsigned short* __restrict__ out, int C, int KT, size_t slab, int ntPerSlab)
{
    tconv_body(in + (size_t)blockIdx.z * slab, out, C, KT,
               blockIdx.z * ntPerSlab, blockIdx.x * 64, blockIdx.y * 64);
}

// merged Wq/Wk/Wv repack: one launch, 3*HQ z-slabs (was 3 underfilled launches)
__global__ __launch_bounds__(256) void tconv_qkv3(const float* __restrict__ Wq,
    const float* __restrict__ Wk, const float* __restrict__ Wv,
    unsigned short* __restrict__ out)
{
    int z = blockIdx.z;
    int which = z / HQ, zz = z - which * HQ;
    const float* src = (which == 0) ? Wq : (which == 1) ? Wk : Wv;
    tconv_body(src + (size_t)zz * EQ * DHQ, out + (size_t)which * EQ * EQ,
               DHQ, 24, zz * 4, blockIdx.x * 64, 0);
}

// ---------------- LayerNorm: fp32 (padded rows) -> PACKED bf16 (KT=24) ------
__global__ __launch_bounds__(256) void ln_kernel(const float* __restrict__ in,
    const float* __restrict__ w, const float* __restrict__ b,
    __hip_bfloat16* __restrict__ out)
{
    int row = blockIdx.x;
    const float* x = in + (size_t)row * EQ;
    int t = threadIdx.x;
    float v0 = x[t];
    float v1 = x[t + 256];
    float v2 = x[t + 512];
    __shared__ float red[256];
    red[t] = v0 + v1 + v2;
    __syncthreads();
    for (int off = 128; off > 0; off >>= 1) {
        if (t < off) red[t] += red[t + off];
        __syncthreads();
    }
    float mu = red[0] * (1.0f / EQ);
    __syncthreads();
    float d0 = v0 - mu, d1 = v1 - mu, d2 = v2 - mu;
    red[t] = d0*d0 + d1*d1 + d2*d2;
    __syncthreads();
    for (int off = 128; off > 0; off >>= 1) {
        if (t < off) red[t] += red[t + off];
        __syncthreads();
    }
    float rs = rsqrtf(red[0] * (1.0f / EQ) + LN_EPS);
    int rt = row >> 4, rsl = row & 15;
    float n0 = d0 * rs * w[t]       + b[t];
    float n1 = d1 * rs * w[t + 256] + b[t + 256];
    float n2 = d2 * rs * w[t + 512] + b[t + 512];
    #pragma unroll
    for (int p = 0; p < 3; ++p) {
        int k = t + (p << 8);
        float val = p == 0 ? n0 : (p == 1 ? n1 : n2);
        int kt = k >> 5, lane = (((k >> 3) & 3) << 4) + rsl, e = k & 7;
        out[pk(rt, 24, kt, lane) + e] = tobf(val);
    }
}

// ---------------- LDS-staged MFMA K-loop (T3/T4: global_load_lds, 3-deep, ---
// counted vmcnt, raw barriers — no vmcnt(0) drain in the main loop) ----------
template<int KT, int RT>
__device__ __forceinline__ void kloop_staged(
    const unsigned short* __restrict__ Apk,
    const unsigned short* __restrict__ Bpk,
    int rtb, int ntb, int tid, unsigned short* sm, f32x4 (&acc)[RT][4])
{
    static_assert(KT >= 3, "need >=3 k-tiles");
    constexpr int AC  = RT * 2;      // A chunks per k-tile (1KB each)
    constexpr int NCH = AC + 8;      // + 8 B chunks
    constexpr int CPW = NCH / 4;     // stage calls per wave per k-tile
    const int lane = tid & 63, w = tid >> 6;
    const int wr = w >> 1, wc = w & 1;
    const int cbase = w * CPW;

    // per-wave global source pointers, advanced by 512 elems per staged tile
    const unsigned short* sp[CPW];
    #pragma unroll
    for (int q = 0; q < CPW; ++q) {
        int c = cbase + q;
        sp[q] = (c < AC) ? Apk + pk(rtb + c, KT, 0, lane)
                         : Bpk + pk(ntb + (c - AC), KT, 0, lane);
    }
    unsigned short* bufs0 = sm;
    unsigned short* bufs1 = sm + NCH * 512;
    unsigned short* bufs2 = sm + 2 * NCH * 512;

    auto stagef = [&](unsigned short* dst) {
        #pragma unroll
        for (int q = 0; q < CPW; ++q) {
            __builtin_amdgcn_global_load_lds(
                (gas_t)sp[q], (las_t)(dst + (cbase + q) * 512), 16, 0, 0);
            sp[q] += 512;
        }
    };
    auto frags = [&](const unsigned short* cur, bf16x8 (&af)[RT], bf16x8 (&bb)[4]) {
        #pragma unroll
        for (int i = 0; i < RT; ++i)
            af[i] = *(const bf16x8*)(cur + (wr * RT + i) * 512 + lane * 8);
        #pragma unroll
        for (int j = 0; j < 4; ++j)
            bb[j] = *(const bf16x8*)(cur + (AC + wc * 4 + j) * 512 + lane * 8);
    };
    auto mf = [&](bf16x8 (&af)[RT], bf16x8 (&bb)[4]) {
        #pragma unroll
        for (int i = 0; i < RT; ++i)
            #pragma unroll
            for (int j = 0; j < 4; ++j)
                acc[i][j] = __builtin_amdgcn_mfma_f32_16x16x32_bf16(af[i], bb[j], acc[i][j], 0, 0, 0);
    };

    stagef(bufs0);                    // tile 0
    stagef(bufs1);                    // tile 1
    unsigned short *cur = bufs0, *nxt = bufs1, *nx2 = bufs2;

    #pragma unroll 1
    for (int kt = 0; kt < KT - 2; ++kt) {
        waitvm<CPW>();                // stage(kt) done; stage(kt+1) in flight
        barx();                       // tile kt visible to all waves
        bf16x8 af[RT], bb[4];
        frags(cur, af, bb);
        stagef(nx2);                  // tile kt+2 (buffer held tile kt-1)
        mf(af, bb);
        unsigned short* t_ = cur; cur = nxt; nxt = nx2; nx2 = t_;
    }
    {   // kt = KT-2 (no more staging)
        waitvm<CPW>();
        barx();
        bf16x8 af[RT], bb[4];
        frags(cur, af, bb);
        mf(af, bb);
        cur = nxt;
    }
    {   // kt = KT-1
        waitvm<0>();
        barx();
        bf16x8 af[RT], bb[4];
        frags(cur, af, bb);
        mf(af, bb);
    }
}

// ---------------- unified packed MFMA GEMM (staged) -------------------------
enum { EPI_NONE = 0, EPI_RES = 1, EPI_BIAS_GELU = 2, EPI_BIAS_RES = 3, EPI_QKV = 4 };

template<int EPI, int KT, int RT>
__global__ __launch_bounds__(256, 3) void mgemm_pk(
    const unsigned short* __restrict__ Apk, const unsigned short* __restrict__ Bpk,
    void* __restrict__ Cm, const float* __restrict__ bias,
    const float* __restrict__ res, int N, int nNT)
{
    constexpr int NCH = RT * 2 + 8;
    __shared__ __align__(16) unsigned short smem[(3 * NCH * 1024) / 2];

    const int nRowT = (RT == 4) ? 52 : 104;        // MP/(RT*32)
    const int g = blockIdx.x & 7;
    const int sIdx = blockIdx.x >> 3;
    const int b0 = (nRowT * g) >> 3, b1 = (nRowT * (g + 1)) >> 3;
    const int colT = sIdx % nNT, rloc = sIdx / nNT;
    if (b0 + rloc >= b1) return;
    const int row0 = (b0 + rloc) * (RT * 32), col0 = colT << 7;

    const int tid = threadIdx.x;
    const int lane = tid & 63;
    const int w = tid >> 6;
    const int wr = w >> 1, wc = w & 1;
    const int l15 = lane & 15, quad = lane >> 4;

    f32x4 acc[RT][4] = {};
    kloop_staged<KT, RT>(Apk, Bpk, row0 >> 4, col0 >> 4, tid, smem, acc);

    if constexpr (EPI == EPI_BIAS_GELU) {
        __syncthreads();              // smem reused as Cs below
        auto Cs = (unsigned short (*)[136])smem;
        #pragma unroll
        for (int j = 0; j < 4; ++j) {
            float bv = bias[col0 + wc * 64 + j * 16 + l15];
            #pragma unroll
            for (int i = 0; i < RT; ++i)
                #pragma unroll
                for (int rg = 0; rg < 4; ++rg) {
                    float v = gelu_f(acc[i][j][rg] + bv);
                    __hip_bfloat16 h = tobf(v);
                    Cs[wr * 64 + i * 16 + quad * 4 + rg][wc * 64 + j * 16 + l15] =
                        *(unsigned short*)&h;
                }
        }
        __syncthreads();
        const int KT2 = N >> 5;
        #pragma unroll
        for (int p = 0; p < 8; ++p) {
            int cc = p * 256 + tid;
            int ln2 = cc & 63, grp = cc >> 6;
            int ktl = grp & 3, rtl = grp >> 2;
            int rowl = rtl * 16 + (ln2 & 15);
            u16x8 v;
            #pragma unroll
            for (int e = 0; e < 8; ++e)
                v[e] = Cs[rowl][ktl * 32 + (ln2 >> 4) * 8 + e];
            *(u16x8*)((unsigned short*)Cm + pk((row0 >> 4) + rtl, KT2, (col0 >> 5) + ktl, ln2)) = v;
        }
    } else if constexpr (EPI == EPI_QKV) {
        // Cm=qpk, bias=kpk, res=vpk (pointer-smuggled)
        unsigned short* qpk = (unsigned short*)Cm;
        unsigned short* kpk = (unsigned short*)(void*)bias;
        unsigned short* vpk = (unsigned short*)(void*)res;
        __syncthreads();              // smem reused as Cs below
        auto Cs = (unsigned short (*)[136])smem;
        #pragma unroll
        for (int j = 0; j < 4; ++j)
            #pragma unroll
            for (int i = 0; i < 4; ++i)
                #pragma unroll
                for (int rg = 0; rg < 4; ++rg) {
                    __hip_bfloat16 h = tobf(acc[i][j][rg]);
                    Cs[wr * 64 + i * 16 + quad * 4 + rg][wc * 64 + j * 16 + l15] =
                        *(unsigned short*)&h;
                }
        __syncthreads();

        const int treg = col0 >> 7;   // 0..5 q, 6..11 k, 12..17 v
        if (treg < 12) {
            unsigned short* dst = (treg < 6) ? qpk : kpk;
            const int h0 = ((col0 % 768) >> 6);
            #pragma unroll
            for (int p = 0; p < 8; ++p) {
                int cc = p * 256 + tid;
                int ln2 = cc & 63, grp = cc >> 6;
                int hl = grp & 1, kt = (grp >> 1) & 1, rtl = grp >> 2;
                int row16 = (row0 >> 4) + rtl;
                int bb = row16 / S16;
                int s16 = row16 - bb * S16;
                int h = h0 + hl;
                u16x8 v;
                #pragma unroll
                for (int e = 0; e < 8; ++e)
                    v[e] = Cs[rtl * 16 + (ln2 & 15)][hl * 64 + kt * 32 + (ln2 >> 4) * 8 + e];
                *(u16x8*)(dst + ((((size_t)(bb * HQ + h) * S16 + s16) * 2 + kt) << 9) + ln2 * 8) = v;
            }
        } else {
            // V -> PV-B-fragment packed slabs per (b,h).
            const int h0 = (col0 - 1536) >> 6;     // block covers heads h0, h0+1
            #pragma unroll
            for (int p = 0; p < 8; ++p) {
                int cc = p * 256 + tid;
                int dloc = cc & 127;               // (w&1)*64 + lane : contiguous
                int g8 = cc >> 7;                  // 0..15, constant per wave
                int gr = row0 + g8 * 8;            // global row of this 8-run
                int bb = gr / SP;
                int tl = gr - bb * SP;             // 0..200, 8-aligned
                int tt = tl >> 5;
                int tsub = (tl >> 3) & 3;
                int h = h0 + (dloc >> 6);
                int dt = (dloc >> 4) & 3;
                int lane2 = tsub * 16 + (dloc & 15);
                u16x8 v;
                #pragma unroll
                for (int e = 0; e < 8; ++e)
                    v[e] = Cs[g8 * 8 + e][dloc];
                *(u16x8*)(vpk + (size_t)(bb * HQ + h) * VPK_SLAB + pk(dt, KTP, tt, lane2)) = v;
            }
        }
    } else {
        #pragma unroll
        for (int j = 0; j < 4; ++j) {
            int c = col0 + wc * 64 + j * 16 + l15;
            float bv = (EPI == EPI_BIAS_RES) ? bias[c] : 0.f;
            #pragma unroll
            for (int i = 0; i < RT; ++i)
                #pragma unroll
                for (int rg = 0; rg < 4; ++rg) {
                    int r = row0 + wr * (RT * 16) + i * 16 + quad * 4 + rg;
                    float v = acc[i][j][rg];
                    size_t idx = (size_t)r * N + c;
                    if (EPI == EPI_BIAS_RES) {
                        ((float*)Cm)[idx] = v + bv + res[idx];
                    } else if (EPI == EPI_RES) {
                        ((float*)Cm)[idx] = v + res[idx];
                    } else {
                        ((__hip_bfloat16*)Cm)[idx] = tobf(v);
                    }
                }
        }
    }
}

// ------------- FUSED attention: QK^T+softmax -> P in LDS -> P@V -> o pk -----
__global__ __launch_bounds__(256) void attn_fused(
    const unsigned short* __restrict__ qpk, const unsigned short* __restrict__ kpk,
    const unsigned short* __restrict__ vpk, unsigned short* __restrict__ opk)
{
    __shared__ float redm[4][64], reds[4][64];
    __shared__ unsigned short Ps[64][264];
    __shared__ unsigned short Cs[64][72];
    const int s0 = blockIdx.x * 64;
    const int bh = blockIdx.y;
    const int b = bh / HQ, h = bh % HQ;
    const int tid = threadIdx.x;
    const int w = tid >> 6, lane = tid & 63;
    const int wr = w >> 1, wc = w & 1;
    const int l15 = lane & 15, quad = lane >> 4;

    const unsigned short* qs = qpk + (size_t)bh * QPK_SLAB;
    const unsigned short* ks = kpk + (size_t)bh * QPK_SLAB;

    f32x4 acc[4][4] = {};
    #pragma unroll
    for (int kk = 0; kk < 2; ++kk) {
        bf16x8 af[4], bfr[4];
        #pragma unroll
        for (int i = 0; i < 4; ++i)
            af[i] = *(const bf16x8*)(qs + ((((s0 >> 4) + i) * 2 + kk) << 9) + lane * 8);
        #pragma unroll
        for (int j = 0; j < 4; ++j)
            bfr[j] = *(const bf16x8*)(ks + (((w * 4 + j) * 2 + kk) << 9) + lane * 8);
        #pragma unroll
        for (int i = 0; i < 4; ++i)
            #pragma unroll
            for (int j = 0; j < 4; ++j)
                acc[i][j] = __builtin_amdgcn_mfma_f32_16x16x32_bf16(af[i], bfr[j], acc[i][j], 0, 0, 0);
    }

    const float scale = 0.07124704998790965f;  // 1/sqrt(197)
    float sc[4][4][4];
    #pragma unroll
    for (int i = 0; i < 4; ++i)
        #pragma unroll
        for (int j = 0; j < 4; ++j) {
            bool ok = (w * 64 + j * 16 + l15) < SQ;
            #pragma unroll
            for (int rg = 0; rg < 4; ++rg)
                sc[i][rg][j] = ok ? acc[i][j][rg] * scale : -1e30f;
        }

    #pragma unroll
    for (int i = 0; i < 4; ++i)
        #pragma unroll
        for (int rg = 0; rg < 4; ++rg) {
            float m = fmaxf(fmaxf(sc[i][rg][0], sc[i][rg][1]), fmaxf(sc[i][rg][2], sc[i][rg][3]));
            #pragma unroll
            for (int d = 1; d < 16; d <<= 1) m = fmaxf(m, __shfl_xor(m, d));
            if (l15 == 0) redm[w][i * 16 + quad * 4 + rg] = m;
        }
    __syncthreads();

    float tot[4][4];
    #pragma unroll
    for (int i = 0; i < 4; ++i)
        #pragma unroll
        for (int rg = 0; rg < 4; ++rg) {
            int row = i * 16 + quad * 4 + rg;
            float m = fmaxf(fmaxf(redm[0][row], redm[1][row]),
                            fmaxf(redm[2][row], redm[3][row]));
            float s = 0.f;
            #pragma unroll
            for (int j = 0; j < 4; ++j) {
                float e = expf(sc[i][rg][j] - m);
                sc[i][rg][j] = e;
                s += e;
            }
            #pragma unroll
            for (int d = 1; d < 16; d <<= 1) s += __shfl_xor(s, d);
            if (l15 == 0) reds[w][row] = s;
            tot[i][rg] = 0.f;
        }
    __syncthreads();

    #pragma unroll
    for (int i = 0; i < 4; ++i)
        #pragma unroll
        for (int rg = 0; rg < 4; ++rg) {
            int row = i * 16 + quad * 4 + rg;
            tot[i][rg] = reds[0][row] + reds[1][row] + reds[2][row] + reds[3][row];
        }

    // normalized P -> LDS, columns XOR-swizzled by row bit3 (conflict-free)
    #pragma unroll
    for (int i = 0; i < 4; ++i)
        #pragma unroll
        for (int rg = 0; rg < 4; ++rg) {
            float inv = 1.0f / tot[i][rg];
            int xr = (quad >> 1) << 4;          // ((row>>3)&1)<<4
            #pragma unroll
            for (int j = 0; j < 4; ++j) {
                __hip_bfloat16 hv = tobf(sc[i][rg][j] * inv);
                Ps[i * 16 + quad * 4 + rg][(w * 64 + j * 16 + l15) ^ xr] = *(unsigned short*)&hv;
            }
        }
    __syncthreads();

    // P @ V : A-frags from Ps (XOR read), B-frags from vpk global (coalesced)
    const unsigned short* vs = vpk + (size_t)bh * VPK_SLAB;
    f32x4 av[2][2] = {};
    bf16x8 vb[2][2];
    #pragma unroll
    for (int j = 0; j < 2; ++j)
        vb[0][j] = *(const bf16x8*)(vs + pk(wc * 2 + j, KTP, 0, lane));
    #pragma unroll
    for (int kk = 0; kk < KTP; ++kk) {
        int cur = kk & 1;
        if (kk + 1 < KTP) {
            #pragma unroll
            for (int j = 0; j < 2; ++j)
                vb[cur ^ 1][j] = *(const bf16x8*)(vs + pk(wc * 2 + j, KTP, kk + 1, lane));
        }
        bf16x8 af[2];
        #pragma unroll
        for (int i = 0; i < 2; ++i) {
            int row = wr * 32 + i * 16 + l15;
            int col = (kk * 32 + quad * 8) ^ (((l15 >> 3) & 1) << 4);
            af[i] = *(const bf16x8*)&Ps[row][col];
        }
        #pragma unroll
        for (int i = 0; i < 2; ++i)
            #pragma unroll
            for (int j = 0; j < 2; ++j)
                av[i][j] = __builtin_amdgcn_mfma_f32_16x16x32_bf16(af[i], vb[cur][j], av[i][j], 0, 0, 0);
    }

    #pragma unroll
    for (int i = 0; i < 2; ++i)
        #pragma unroll
        for (int j = 0; j < 2; ++j)
            #pragma unroll
            for (int rg = 0; rg < 4; ++rg) {
                __hip_bfloat16 hv = tobf(av[i][j][rg]);
                Cs[wr * 32 + i * 16 + quad * 4 + rg][wc * 32 + j * 16 + l15] =
                    *(unsigned short*)&hv;
            }
    __syncthreads();

    const int rt0 = b * S16 + (s0 >> 4);
    const int kt0 = h * 2;
    int validRt = (SP - s0) >> 4; if (validRt > 4) validRt = 4;
    #pragma unroll
    for (int p = 0; p < 2; ++p) {
        int cc = p * 256 + tid;
        int ln2 = cc & 63, grp = cc >> 6;
        int ktl = grp & 1, rtl = grp >> 1;
        if (rtl < validRt) {
            int rowl = rtl * 16 + (ln2 & 15);
            int colb = ktl * 32 + (ln2 >> 4) * 8;
            u16x8 v;
            #pragma unroll
            for (int e = 0; e < 8; ++e)
                v[e] = Cs[rowl][colb + e];
            *(u16x8*)(opk + pk(rt0 + rtl, 24, kt0 + ktl, ln2)) = v;
        }
    }
}

// ---------------- classifier: split-K logits + softmax ----------------------
__global__ __launch_bounds__(256) void logits_kernel(
    const float* __restrict__ hbuf, const float* __restrict__ Wc,
    const float* __restrict__ bc, float* __restrict__ logits)
{
    __shared__ __align__(16) float hs[768];
    __shared__ float red[256];
    int b = blockIdx.y;
    int tid = threadIdx.x;
    const float* hr = hbuf + (size_t)b * SP * EQ;   // s=0 row
    for (int p = tid; p < 192; p += 256)
        *(float4*)&hs[p << 2] = *(const float4*)(hr + (p << 2));
    __syncthreads();
    int cl = tid & 31, ks = tid >> 5;
    int c = blockIdx.x * 32 + cl;
    int cs = (c < CQ) ? c : 0;
    float s = 0.f;
    int e0 = ks * 96;
    #pragma unroll 8
    for (int e = 0; e < 96; ++e)
        s = fmaf(hs[e0 + e], Wc[(size_t)(e0 + e) * CQ + cs], s);
    red[tid] = s;
    __syncthreads();
    for (int off = 128; off >= 32; off >>= 1) {
        if (tid < off) red[tid] += red[tid + off];
        __syncthreads();
    }
    if (tid < 32 && c < CQ)
        logits[(size_t)b * CQ + c] = red[tid] + bc[c];
}

__global__ __launch_bounds__(256) void smax_kernel(
    const float* __restrict__ logits, float* __restrict__ out)
{
    __shared__ float red[256];
    int b = blockIdx.x;
    int t = threadIdx.x;
    const float* lp = logits + (size_t)b * CQ;
    float lg[4];
    #pragma unroll
    for (int j = 0; j < 4; ++j) {
        int c = t + j * 256;
        lg[j] = (c < CQ) ? lp[c] : -1e30f;
    }
    float m = fmaxf(fmaxf(lg[0], lg[1]), fmaxf(lg[2], lg[3]));
    red[t] = m;
    __syncthreads();
    for (int off = 128; off; off >>= 1) {
        if (t < off) red[t] = fmaxf(red[t], red[t + off]);
        __syncthreads();
    }
    m = red[0];
    __syncthreads();
    float ex[4], s = 0.f;
    #pragma unroll
    for (int j = 0; j < 4; ++j) {
        ex[j] = (t + j * 256 < CQ) ? expf(lg[j] - m) : 0.f;
        s += ex[j];
    }
    red[t] = s;
    __syncthreads();
    for (int off = 128; off; off >>= 1) {
        if (t < off) red[t] += red[t + off];
        __syncthreads();
    }
    float inv = 1.0f / red[0];
    #pragma unroll
    for (int j = 0; j < 4; ++j)
        if (t + j * 256 < CQ) out[(size_t)b * CQ + t + j * 256] = ex[j] * inv;
}

extern "C" void kernel_launch(void* const* d_in, const int* in_sizes, int n_in,
                              void* d_out, int out_size, void* d_ws, size_t ws_size,
                              hipStream_t stream)
{
    const float* x     = (const float*)d_in[0];
    const float* Wk    = (const float*)d_in[1];
    const float* Wq    = (const float*)d_in[2];
    const float* Wv    = (const float*)d_in[3];
    const float* Wconv = (const float*)d_in[4];
    const float* ln1w  = (const float*)d_in[5];
    const float* ln1b  = (const float*)d_in[6];
    const float* ln2w  = (const float*)d_in[7];
    const float* ln2b  = (const float*)d_in[8];
    const float* W1    = (const float*)d_in[9];
    const float* b1    = (const float*)d_in[10];
    const float* W2    = (const float*)d_in[11];
    const float* b2    = (const float*)d_in[12];
    const float* Wc    = (const float*)d_in[13];
    const float* bc    = (const float*)d_in[14];
    float* out = (float*)d_out;

    const size_t MPE = (size_t)MP * EQ;

    float* w = (float*)d_ws;
    float* bh    = w; w += MPE;
    float* res1  = w; w += MPE;
    float* logit = w; w += (size_t)BQ * CQ;
    unsigned short* qpk  = (unsigned short*)w;
    unsigned short* kpk  = qpk + QPK_TOT;
    unsigned short* vpk  = kpk + QPK_TOT;
    unsigned short* actb = vpk + VPK_TOT;           // packed activations
    unsigned short* ffh  = actb + MPE;              // packed FF hidden (MP x FQ)
    unsigned short* wbuf = ffh + (size_t)MP * FQ;

    const size_t WQKV = (size_t)EQ * EQ;
    unsigned short* WcvT = wbuf;                    // phase B overlays
    unsigned short* W1T  = wbuf + WQKV;
    unsigned short* W2T  = W1T + (size_t)EQ * FQ;

    copy_pad<<<BSQ, 256, 0, stream>>>(x, bh);

    for (int l = 0; l < LQ; ++l) {
        tconv_qkv3<<<dim3(12, 1, 3 * HQ), 256, 0, stream>>>(
            Wq + (size_t)l * HQ * EQ * DHQ, Wk + (size_t)l * HQ * EQ * DHQ,
            Wv + (size_t)l * HQ * EQ * DHQ, wbuf);

        ln_kernel<<<MP, 256, 0, stream>>>(bh, ln1w + l * EQ, ln1b + l * EQ, (__hip_bfloat16*)actb);

        mgemm_pk<EPI_QKV, 24, 4><<<8 * 7 * 18, 256, 0, stream>>>(
            actb, wbuf, qpk, (const float*)kpk, (const float*)vpk, QKV3, 18);

        tconv_pk<<<dim3(12, 12, 1), 256, 0, stream>>>(Wconv + (size_t)l * EQ * EQ, WcvT, EQ, 24, 0, 0);
        tconv_pk<<<dim3(12, 32, 1), 256, 0, stream>>>(W1 + (size_t)l * EQ * FQ, W1T, FQ, 24, 0, 0);
        tconv_pk<<<dim3(32, 12, 1), 256, 0, stream>>>(W2 + (size_t)l * FQ * EQ, W2T, EQ, 64, 0, 0);

        attn_fused<<<dim3(4, BQ * HQ), 256, 0, stream>>>(qpk, kpk, vpk, actb);

        mgemm_pk<EPI_RES, 24, 2><<<8 * 13 * 6, 256, 0, stream>>>(
            actb, WcvT, res1, nullptr, bh, EQ, 6);

        ln_kernel<<<MP, 256, 0, stream>>>(res1, ln2w + l * EQ, ln2b + l * EQ, (__hip_bfloat16*)actb);

        mgemm_pk<EPI_BIAS_GELU, 24, 4><<<8 * 7 * 16, 256, 0, stream>>>(
            actb, W1T, ffh, b1 + l * FQ, nullptr, FQ, 16);
        mgemm_pk<EPI_BIAS_RES, 64, 2><<<8 * 13 * 6, 256, 0, stream>>>(
            ffh, W2T, bh, b2 + l * EQ, res1, EQ, 6);
    }
    logits_kernel<<<dim3(32, BQ), 256, 0, stream>>>(bh, Wc, bc, logit);
    smax_kernel<<<BQ, 256, 0, stream>>>(logit, out);
}

// Round 5
// 793.764 us; speedup vs baseline: 1.3873x; 1.1703x over previous
//
#include <hip/hip_runtime.h>
#include <hip/hip_bf16.h>
#include <math.h>

#define BQ 32
#define SQ 197
#define EQ 768
#define HQ 12
#define DHQ 64
#define FQ 2048
#define LQ 4
#define CQ 1000
#define BSQ (BQ*SQ)     // 6304
#define SP 208          // padded rows per batch (13 * 16)
#define S16 13          // 16-row tiles per batch
#define MP (BQ*SP)      // 6656 padded total rows
#define QKV3 2304
#define KTP 7           // t-chunks of 32 (224) for P / V
#define LN_EPS 1e-5f

typedef __bf16 bf16x8 __attribute__((ext_vector_type(8)));
typedef float f32x4 __attribute__((ext_vector_type(4)));
typedef unsigned short u16x8 __attribute__((ext_vector_type(8)));

typedef const __attribute__((address_space(1))) unsigned int* gas_t;
typedef __attribute__((address_space(3))) unsigned int* las_t;

__device__ __forceinline__ __hip_bfloat16 tobf(float f) { return __float2bfloat16(f); }

// Packed fragment layout: chunk of 8 bf16 for (row-tile rt, k-tile kt, lane):
//   buf[pk(rt,KT,kt,lane)+e] <-> A[rt*16+(lane&15)][kt*32+(lane>>4)*8+e]
__device__ __forceinline__ size_t pk(int rt, int KT, int kt, int lane) {
    return (((size_t)rt * KT + kt) * 64 + (size_t)lane) * 8;
}

// sizes (elems)
#define QPK_SLAB (S16*2*512)            // per (b,h): 13 rt x 2 kt x 512
#define QPK_TOT  ((size_t)BQ*HQ*QPK_SLAB + 4096)
#define VPK_SLAB (4*KTP*512)            // per (b,h): 4 dt x 7 tt x 512
#define VPK_TOT  ((size_t)BQ*HQ*VPK_SLAB + 4096)

template<int N>
__device__ __forceinline__ void waitvm() {
    asm volatile("s_waitcnt vmcnt(%0)" :: "n"(N) : "memory");
}
__device__ __forceinline__ void barx() {
    asm volatile("" ::: "memory");
    __builtin_amdgcn_s_barrier();
    asm volatile("" ::: "memory");
}
// wave-local LDS fence: cross-LANE LDS RAW within one wave needs an explicit
// lgkmcnt drain + sched_barrier (rule #18).
__device__ __forceinline__ void lds_fence() {
    asm volatile("s_waitcnt lgkmcnt(0)" ::: "memory");
    __builtin_amdgcn_sched_barrier(0);
}

// fast exact-form GELU: erf via A&S 7.1.26 (|erf err| < 1.5e-7)
__device__ __forceinline__ float gelu_f(float v) {
    float ax = fabsf(v) * 0.70710678118654752f;
    float t  = __builtin_amdgcn_rcpf(1.0f + 0.3275911f * ax);
    float p  = ((((1.061405429f * t - 1.453152027f) * t + 1.421413741f) * t
               - 0.284496736f) * t + 0.254829592f) * t;
    float e  = __expf(-ax * ax);
    float er = 1.0f - p * e;                 // erf(|x|)
    return v * (0.5f * (1.0f + copysignf(er, v)));
}

// ---------------- copy x into padded residual stream ------------------------
__global__ __launch_bounds__(256) void copy_pad(const float* __restrict__ x,
    float* __restrict__ bh)
{
    int r = blockIdx.x;
    int b = r / SQ, s = r % SQ;
    const float* src = x + (size_t)r * EQ;
    float* dst = bh + ((size_t)b * SP + s) * EQ;
    int t = threadIdx.x;
    dst[t] = src[t];
    dst[t + 256] = src[t + 256];
    dst[t + 512] = src[t + 512];
}

// ---------------- transpose + convert + PACK weights ------------------------
__device__ __forceinline__ void tconv_body(const float* __restrict__ ip,
    unsigned short* __restrict__ out, int C, int KT, int ntb_base, int r0, int c0)
{
    __shared__ float tile[64][65];
    int t = threadIdx.x;
    int tc = t & 63, tr = t >> 6;
    #pragma unroll
    for (int p = 0; p < 16; ++p) {
        int r = p * 4 + tr;
        tile[r][tc] = ip[(size_t)(r0 + r) * C + c0 + tc];
    }
    __syncthreads();
    int ntb = ntb_base + (c0 >> 4);
    int ktb = r0 >> 5;
    #pragma unroll
    for (int p = 0; p < 2; ++p) {
        int cc = p * 256 + t;
        int lane = cc & 63, grp = cc >> 6;
        int ktl = grp & 1, ntl = grp >> 1;
        int er = ktl * 32 + (lane >> 4) * 8;
        int dc = ntl * 16 + (lane & 15);
        u16x8 v;
        #pragma unroll
        for (int e = 0; e < 8; ++e) {
            __hip_bfloat16 h = tobf(tile[er + e][dc]);
            v[e] = *(unsigned short*)&h;
        }
        *(u16x8*)(out + pk(ntb + ntl, KT, ktb + ktl, lane)) = v;
    }
}

__global__ __launch_bounds__(256) void tconv_pk(const float* __restrict__ in,
    unsigned short* __restrict__ out, int C, int KT, size_t slab, int ntPerSlab)
{
    tconv_body(in + (size_t)blockIdx.z * slab, out, C, KT,
               blockIdx.z * ntPerSlab, blockIdx.x * 64, blockIdx.y * 64);
}

// merged Wq/Wk/Wv repack: one launch, 3*HQ z-slabs
__global__ __launch_bounds__(256) void tconv_qkv3(const float* __restrict__ Wq,
    const float* __restrict__ Wk, const float* __restrict__ Wv,
    unsigned short* __restrict__ out)
{
    int z = blockIdx.z;
    int which = z / HQ, zz = z - which * HQ;
    const float* src = (which == 0) ? Wq : (which == 1) ? Wk : Wv;
    tconv_body(src + (size_t)zz * EQ * DHQ, out + (size_t)which * EQ * EQ,
               DHQ, 24, zz * 4, blockIdx.x * 64, 0);
}

// ---------------- LayerNorm: fp32 (padded rows) -> PACKED bf16 (KT=24) ------
__global__ __launch_bounds__(256) void ln_kernel(const float* __restrict__ in,
    const float* __restrict__ w, const float* __restrict__ b,
    __hip_bfloat16* __restrict__ out)
{
    int row = blockIdx.x;
    const float* x = in + (size_t)row * EQ;
    int t = threadIdx.x;
    float v0 = x[t];
    float v1 = x[t + 256];
    float v2 = x[t + 512];
    __shared__ float red[256];
    red[t] = v0 + v1 + v2;
    __syncthreads();
    for (int off = 128; off > 0; off >>= 1) {
        if (t < off) red[t] += red[t + off];
        __syncthreads();
    }
    float mu = red[0] * (1.0f / EQ);
    __syncthreads();
    float d0 = v0 - mu, d1 = v1 - mu, d2 = v2 - mu;
    red[t] = d0*d0 + d1*d1 + d2*d2;
    __syncthreads();
    for (int off = 128; off > 0; off >>= 1) {
        if (t < off) red[t] += red[t + off];
        __syncthreads();
    }
    float rs = rsqrtf(red[0] * (1.0f / EQ) + LN_EPS);
    int rt = row >> 4, rsl = row & 15;
    float n0 = d0 * rs * w[t]       + b[t];
    float n1 = d1 * rs * w[t + 256] + b[t + 256];
    float n2 = d2 * rs * w[t + 512] + b[t + 512];
    #pragma unroll
    for (int p = 0; p < 3; ++p) {
        int k = t + (p << 8);
        float val = p == 0 ? n0 : (p == 1 ? n1 : n2);
        int kt = k >> 5, lane = (((k >> 3) & 3) << 4) + rsl, e = k & 7;
        out[pk(rt, 24, kt, lane) + e] = tobf(val);
    }
}

// ---------------- LDS-staged MFMA K-loop (T3/T4) ----------------------------
template<int KT, int RT>
__device__ __forceinline__ void kloop_staged(
    const unsigned short* __restrict__ Apk,
    const unsigned short* __restrict__ Bpk,
    int rtb, int ntb, int tid, unsigned short* sm, f32x4 (&acc)[RT][4])
{
    static_assert(KT >= 3, "need >=3 k-tiles");
    constexpr int AC  = RT * 2;      // A chunks per k-tile (1KB each)
    constexpr int NCH = AC + 8;      // + 8 B chunks
    constexpr int CPW = NCH / 4;     // stage calls per wave per k-tile
    const int lane = tid & 63, w = tid >> 6;
    const int wr = w >> 1, wc = w & 1;
    const int cbase = w * CPW;

    const unsigned short* sp[CPW];
    #pragma unroll
    for (int q = 0; q < CPW; ++q) {
        int c = cbase + q;
        sp[q] = (c < AC) ? Apk + pk(rtb + c, KT, 0, lane)
                         : Bpk + pk(ntb + (c - AC), KT, 0, lane);
    }
    unsigned short* bufs0 = sm;
    unsigned short* bufs1 = sm + NCH * 512;
    unsigned short* bufs2 = sm + 2 * NCH * 512;

    auto stagef = [&](unsigned short* dst) {
        #pragma unroll
        for (int q = 0; q < CPW; ++q) {
            __builtin_amdgcn_global_load_lds(
                (gas_t)sp[q], (las_t)(dst + (cbase + q) * 512), 16, 0, 0);
            sp[q] += 512;
        }
    };
    auto frags = [&](const unsigned short* cur, bf16x8 (&af)[RT], bf16x8 (&bb)[4]) {
        #pragma unroll
        for (int i = 0; i < RT; ++i)
            af[i] = *(const bf16x8*)(cur + (wr * RT + i) * 512 + lane * 8);
        #pragma unroll
        for (int j = 0; j < 4; ++j)
            bb[j] = *(const bf16x8*)(cur + (AC + wc * 4 + j) * 512 + lane * 8);
    };
    auto mf = [&](bf16x8 (&af)[RT], bf16x8 (&bb)[4]) {
        #pragma unroll
        for (int i = 0; i < RT; ++i)
            #pragma unroll
            for (int j = 0; j < 4; ++j)
                acc[i][j] = __builtin_amdgcn_mfma_f32_16x16x32_bf16(af[i], bb[j], acc[i][j], 0, 0, 0);
    };

    stagef(bufs0);                    // tile 0
    stagef(bufs1);                    // tile 1
    unsigned short *cur = bufs0, *nxt = bufs1, *nx2 = bufs2;

    #pragma unroll 1
    for (int kt = 0; kt < KT - 2; ++kt) {
        waitvm<CPW>();                // stage(kt) done; stage(kt+1) in flight
        barx();
        bf16x8 af[RT], bb[4];
        frags(cur, af, bb);
        stagef(nx2);                  // tile kt+2
        mf(af, bb);
        unsigned short* t_ = cur; cur = nxt; nxt = nx2; nx2 = t_;
    }
    {   // kt = KT-2
        waitvm<CPW>();
        barx();
        bf16x8 af[RT], bb[4];
        frags(cur, af, bb);
        mf(af, bb);
        cur = nxt;
    }
    {   // kt = KT-1
        waitvm<0>();
        barx();
        bf16x8 af[RT], bb[4];
        frags(cur, af, bb);
        mf(af, bb);
    }
}

// ---------------- unified packed MFMA GEMM (staged) -------------------------
enum { EPI_NONE = 0, EPI_RES = 1, EPI_BIAS_GELU = 2, EPI_BIAS_RES = 3, EPI_QKV = 4 };

template<int EPI, int KT, int RT>
__global__ __launch_bounds__(256, 3) void mgemm_pk(
    const unsigned short* __restrict__ Apk, const unsigned short* __restrict__ Bpk,
    void* __restrict__ Cm, const float* __restrict__ bias,
    const float* __restrict__ res, int N, int nNT)
{
    constexpr int NCH = RT * 2 + 8;
    __shared__ __align__(16) unsigned short smem[(3 * NCH * 1024) / 2];

    const int nRowT = (RT == 4) ? 52 : 104;        // MP/(RT*32)
    const int g = blockIdx.x & 7;
    const int sIdx = blockIdx.x >> 3;
    const int b0 = (nRowT * g) >> 3, b1 = (nRowT * (g + 1)) >> 3;
    const int colT = sIdx % nNT, rloc = sIdx / nNT;
    if (b0 + rloc >= b1) return;
    const int row0 = (b0 + rloc) * (RT * 32), col0 = colT << 7;

    const int tid = threadIdx.x;
    const int lane = tid & 63;
    const int w = tid >> 6;
    const int wr = w >> 1, wc = w & 1;
    const int l15 = lane & 15, quad = lane >> 4;

    f32x4 acc[RT][4] = {};
    kloop_staged<KT, RT>(Apk, Bpk, row0 >> 4, col0 >> 4, tid, smem, acc);

    if constexpr (EPI == EPI_BIAS_GELU) {
        __syncthreads();              // smem reused as Cs below
        auto Cs = (unsigned short (*)[136])smem;
        #pragma unroll
        for (int j = 0; j < 4; ++j) {
            float bv = bias[col0 + wc * 64 + j * 16 + l15];
            #pragma unroll
            for (int i = 0; i < RT; ++i)
                #pragma unroll
                for (int rg = 0; rg < 4; ++rg) {
                    float v = gelu_f(acc[i][j][rg] + bv);
                    __hip_bfloat16 h = tobf(v);
                    Cs[wr * 64 + i * 16 + quad * 4 + rg][wc * 64 + j * 16 + l15] =
                        *(unsigned short*)&h;
                }
        }
        __syncthreads();
        const int KT2 = N >> 5;
        #pragma unroll
        for (int p = 0; p < 8; ++p) {
            int cc = p * 256 + tid;
            int ln2 = cc & 63, grp = cc >> 6;
            int ktl = grp & 3, rtl = grp >> 2;
            int rowl = rtl * 16 + (ln2 & 15);
            u16x8 v;
            #pragma unroll
            for (int e = 0; e < 8; ++e)
                v[e] = Cs[rowl][ktl * 32 + (ln2 >> 4) * 8 + e];
            *(u16x8*)((unsigned short*)Cm + pk((row0 >> 4) + rtl, KT2, (col0 >> 5) + ktl, ln2)) = v;
        }
    } else if constexpr (EPI == EPI_QKV) {
        unsigned short* qpk = (unsigned short*)Cm;
        unsigned short* kpk = (unsigned short*)(void*)bias;
        unsigned short* vpk = (unsigned short*)(void*)res;
        __syncthreads();              // smem reused as Cs below
        auto Cs = (unsigned short (*)[136])smem;
        #pragma unroll
        for (int j = 0; j < 4; ++j)
            #pragma unroll
            for (int i = 0; i < 4; ++i)
                #pragma unroll
                for (int rg = 0; rg < 4; ++rg) {
                    __hip_bfloat16 h = tobf(acc[i][j][rg]);
                    Cs[wr * 64 + i * 16 + quad * 4 + rg][wc * 64 + j * 16 + l15] =
                        *(unsigned short*)&h;
                }
        __syncthreads();

        const int treg = col0 >> 7;   // 0..5 q, 6..11 k, 12..17 v
        if (treg < 12) {
            unsigned short* dst = (treg < 6) ? qpk : kpk;
            const int h0 = ((col0 % 768) >> 6);
            #pragma unroll
            for (int p = 0; p < 8; ++p) {
                int cc = p * 256 + tid;
                int ln2 = cc & 63, grp = cc >> 6;
                int hl = grp & 1, kt = (grp >> 1) & 1, rtl = grp >> 2;
                int row16 = (row0 >> 4) + rtl;
                int bb = row16 / S16;
                int s16 = row16 - bb * S16;
                int h = h0 + hl;
                u16x8 v;
                #pragma unroll
                for (int e = 0; e < 8; ++e)
                    v[e] = Cs[rtl * 16 + (ln2 & 15)][hl * 64 + kt * 32 + (ln2 >> 4) * 8 + e];
                *(u16x8*)(dst + ((((size_t)(bb * HQ + h) * S16 + s16) * 2 + kt) << 9) + ln2 * 8) = v;
            }
        } else {
            const int h0 = (col0 - 1536) >> 6;     // block covers heads h0, h0+1
            #pragma unroll
            for (int p = 0; p < 8; ++p) {
                int cc = p * 256 + tid;
                int dloc = cc & 127;
                int g8 = cc >> 7;
                int gr = row0 + g8 * 8;
                int bb = gr / SP;
                int tl = gr - bb * SP;
                int tt = tl >> 5;
                int tsub = (tl >> 3) & 3;
                int h = h0 + (dloc >> 6);
                int dt = (dloc >> 4) & 3;
                int lane2 = tsub * 16 + (dloc & 15);
                u16x8 v;
                #pragma unroll
                for (int e = 0; e < 8; ++e)
                    v[e] = Cs[g8 * 8 + e][dloc];
                *(u16x8*)(vpk + (size_t)(bb * HQ + h) * VPK_SLAB + pk(dt, KTP, tt, lane2)) = v;
            }
        }
    } else {
        #pragma unroll
        for (int j = 0; j < 4; ++j) {
            int c = col0 + wc * 64 + j * 16 + l15;
            float bv = (EPI == EPI_BIAS_RES) ? bias[c] : 0.f;
            #pragma unroll
            for (int i = 0; i < RT; ++i)
                #pragma unroll
                for (int rg = 0; rg < 4; ++rg) {
                    int r = row0 + wr * (RT * 16) + i * 16 + quad * 4 + rg;
                    float v = acc[i][j][rg];
                    size_t idx = (size_t)r * N + c;
                    if (EPI == EPI_BIAS_RES) {
                        ((float*)Cm)[idx] = v + bv + res[idx];
                    } else if (EPI == EPI_RES) {
                        ((float*)Cm)[idx] = v + res[idx];
                    } else {
                        ((__hip_bfloat16*)Cm)[idx] = tobf(v);
                    }
                }
        }
    }
}

// ------------- FUSED attention: barrier-free, one wave per 16-row Q tile ----
// Wave owns rows [rt*16, rt*16+16) x all 208 K cols: QK^T (13 nt x 2 kt MFMA),
// in-wave softmax (shfl over 16 lanes), P -> wave-private LDS (unnormalized),
// PV (7 kt x 4 dt MFMA), normalize av, wave-private LDS transpose -> opk.
// Zero __syncthreads; only wave-local lgkmcnt fences.
// PV consumes 7x32=224 t-columns; P written for t<208 and ZERO-FILLED for
// t=208..223 (R2 bug: those LDS cols were uninitialized -> NaN).
__global__ __launch_bounds__(128, 4) void attn_fused(
    const unsigned short* __restrict__ qpk, const unsigned short* __restrict__ kpk,
    const unsigned short* __restrict__ vpk, unsigned short* __restrict__ opk)
{
    __shared__ unsigned short Ps[2][16][240];   // P, col XOR-swizzled by row bit3
    __shared__ unsigned short Cs[2][16][72];    // output transpose scratch
    const int bh = blockIdx.x;
    const int b = bh / HQ, h = bh - b * HQ;
    const int tid = threadIdx.x;
    const int w = tid >> 6, lane = tid & 63;
    const int l15 = lane & 15, quad = lane >> 4;
    const int rt = blockIdx.y * 2 + w;          // 0..13; 13 is empty
    if (rt >= S16) return;

    const unsigned short* qs = qpk + (size_t)bh * QPK_SLAB;
    const unsigned short* ks = kpk + (size_t)bh * QPK_SLAB;
    const unsigned short* vs = vpk + (size_t)bh * VPK_SLAB;

    // Q fragments (2 k-tiles)
    bf16x8 af0 = *(const bf16x8*)(qs + ((rt * 2 + 0) << 9) + lane * 8);
    bf16x8 af1 = *(const bf16x8*)(qs + ((rt * 2 + 1) << 9) + lane * 8);

    // QK^T over all 13 col-tiles, 1-deep K prefetch
    f32x4 acc[13] = {};
    bf16x8 kc0 = *(const bf16x8*)(ks + (0 << 9) + lane * 8);
    bf16x8 kc1 = *(const bf16x8*)(ks + (1 << 9) + lane * 8);
    #pragma unroll
    for (int j = 0; j < 13; ++j) {
        bf16x8 kn0, kn1;
        if (j + 1 < 13) {
            kn0 = *(const bf16x8*)(ks + (((j + 1) * 2 + 0) << 9) + lane * 8);
            kn1 = *(const bf16x8*)(ks + (((j + 1) * 2 + 1) << 9) + lane * 8);
        }
        __builtin_amdgcn_s_setprio(1);
        acc[j] = __builtin_amdgcn_mfma_f32_16x16x32_bf16(af0, kc0, acc[j], 0, 0, 0);
        acc[j] = __builtin_amdgcn_mfma_f32_16x16x32_bf16(af1, kc1, acc[j], 0, 0, 0);
        __builtin_amdgcn_s_setprio(0);
        kc0 = kn0; kc1 = kn1;
    }

    // prefetch V k-tile 0 (lands during softmax)
    bf16x8 vb[4];
    #pragma unroll
    for (int d = 0; d < 4; ++d)
        vb[d] = *(const bf16x8*)(vs + pk(d, KTP, 0, lane));

    // in-wave softmax: rows quad*4+rg live in 16 lanes (same quad, all l15)
    const float scale = 0.07124704998790965f;  // 1/sqrt(197)
    const int xr = (quad & 2) << 3;            // row-bit3 col swizzle
    const unsigned short zbf = 0;              // bf16 +0.0
    float inv[4];
    #pragma unroll
    for (int rg = 0; rg < 4; ++rg) {
        float y[13];
        float m = -1e30f;
        #pragma unroll
        for (int j = 0; j < 13; ++j) {
            float v = acc[j][rg] * scale;
            if (j == 12) v = (l15 < 5) ? v : -1e30f;   // cols 197..207 masked
            y[j] = v;
            m = fmaxf(m, v);
        }
        #pragma unroll
        for (int d = 1; d < 16; d <<= 1) m = fmaxf(m, __shfl_xor(m, d));
        float s = 0.f;
        #pragma unroll
        for (int j = 0; j < 13; ++j) {
            float e = __expf(y[j] - m);        // e in [0,1] -> bf16-safe
            s += e;
            __hip_bfloat16 hv = tobf(e);
            Ps[w][quad * 4 + rg][(j * 16 + l15) ^ xr] = *(unsigned short*)&hv;
        }
        // zero-fill pad tile j=13 (t=208..223) — PV reads these columns
        Ps[w][quad * 4 + rg][(208 + l15) ^ xr] = zbf;
        #pragma unroll
        for (int d = 1; d < 16; d <<= 1) s += __shfl_xor(s, d);
        inv[rg] = 1.0f / s;                    // applied to av post-PV
    }
    lds_fence();                               // P visible to all lanes of wave

    // P @ V : A-frag from wave-private Ps, B-frags from vpk (1-deep prefetch)
    f32x4 av[4] = {};
    #pragma unroll
    for (int kk = 0; kk < KTP; ++kk) {
        bf16x8 vn[4];
        if (kk + 1 < KTP) {
            #pragma unroll
            for (int d = 0; d < 4; ++d)
                vn[d] = *(const bf16x8*)(vs + pk(d, KTP, kk + 1, lane));
        }
        int col = (kk * 32 + quad * 8) ^ ((l15 & 8) << 1);
        bf16x8 pf = *(const bf16x8*)&Ps[w][l15][col];
        __builtin_amdgcn_s_setprio(1);
        #pragma unroll
        for (int d = 0; d < 4; ++d)
            av[d] = __builtin_amdgcn_mfma_f32_16x16x32_bf16(pf, vb[d], av[d], 0, 0, 0);
        __builtin_amdgcn_s_setprio(0);
        #pragma unroll
        for (int d = 0; d < 4; ++d) vb[d] = vn[d];
    }

    // normalize + transpose via wave-private Cs -> packed opk (A-frag layout)
    #pragma unroll
    for (int d = 0; d < 4; ++d)
        #pragma unroll
        for (int rg = 0; rg < 4; ++rg) {
            __hip_bfloat16 hv = tobf(av[d][rg] * inv[rg]);
            Cs[w][quad * 4 + rg][d * 16 + l15] = *(unsigned short*)&hv;
        }
    lds_fence();

    const int rtg = b * S16 + rt;
    #pragma unroll
    for (int ktl = 0; ktl < 2; ++ktl) {
        u16x8 v;
        #pragma unroll
        for (int e = 0; e < 8; ++e)
            v[e] = Cs[w][l15][ktl * 32 + quad * 8 + e];
        *(u16x8*)(opk + pk(rtg, 24, h * 2 + ktl, lane)) = v;
    }
}

// ---------------- classifier: split-K logits + softmax ----------------------
__global__ __launch_bounds__(256) void logits_kernel(
    const float* __restrict__ hbuf, const float* __restrict__ Wc,
    const float* __restrict__ bc, float* __restrict__ logits)
{
    __shared__ __align__(16) float hs[768];
    __shared__ float red[256];
    int b = blockIdx.y;
    int tid = threadIdx.x;
    const float* hr = hbuf + (size_t)b * SP * EQ;   // s=0 row
    for (int p = tid; p < 192; p += 256)
        *(float4*)&hs[p << 2] = *(const float4*)(hr + (p << 2));
    __syncthreads();
    int cl = tid & 31, ks = tid >> 5;
    int c = blockIdx.x * 32 + cl;
    int cs = (c < CQ) ? c : 0;
    float s = 0.f;
    int e0 = ks * 96;
    #pragma unroll 8
    for (int e = 0; e < 96; ++e)
        s = fmaf(hs[e0 + e], Wc[(size_t)(e0 + e) * CQ + cs], s);
    red[tid] = s;
    __syncthreads();
    for (int off = 128; off >= 32; off >>= 1) {
        if (tid < off) red[tid] += red[tid + off];
        __syncthreads();
    }
    if (tid < 32 && c < CQ)
        logits[(size_t)b * CQ + c] = red[tid] + bc[c];
}

__global__ __launch_bounds__(256) void smax_kernel(
    const float* __restrict__ logits, float* __restrict__ out)
{
    __shared__ float red[256];
    int b = blockIdx.x;
    int t = threadIdx.x;
    const float* lp = logits + (size_t)b * CQ;
    float lg[4];
    #pragma unroll
    for (int j = 0; j < 4; ++j) {
        int c = t + j * 256;
        lg[j] = (c < CQ) ? lp[c] : -1e30f;
    }
    float m = fmaxf(fmaxf(lg[0], lg[1]), fmaxf(lg[2], lg[3]));
    red[t] = m;
    __syncthreads();
    for (int off = 128; off; off >>= 1) {
        if (t < off) red[t] = fmaxf(red[t], red[t + off]);
        __syncthreads();
    }
    m = red[0];
    __syncthreads();
    float ex[4], s = 0.f;
    #pragma unroll
    for (int j = 0; j < 4; ++j) {
        ex[j] = (t + j * 256 < CQ) ? __expf(lg[j] - m) : 0.f;
        s += ex[j];
    }
    red[t] = s;
    __syncthreads();
    for (int off = 128; off; off >>= 1) {
        if (t < off) red[t] += red[t + off];
        __syncthreads();
    }
    float inv = 1.0f / red[0];
    #pragma unroll
    for (int j = 0; j < 4; ++j)
        if (t + j * 256 < CQ) out[(size_t)b * CQ + t + j * 256] = ex[j] * inv;
}

extern "C" void kernel_launch(void* const* d_in, const int* in_sizes, int n_in,
                              void* d_out, int out_size, void* d_ws, size_t ws_size,
                              hipStream_t stream)
{
    const float* x     = (const float*)d_in[0];
    const float* Wk    = (const float*)d_in[1];
    const float* Wq    = (const float*)d_in[2];
    const float* Wv    = (const float*)d_in[3];
    const float* Wconv = (const float*)d_in[4];
    const float* ln1w  = (const float*)d_in[5];
    const float* ln1b  = (const float*)d_in[6];
    const float* ln2w  = (const float*)d_in[7];
    const float* ln2b  = (const float*)d_in[8];
    const float* W1    = (const float*)d_in[9];
    const float* b1    = (const float*)d_in[10];
    const float* W2    = (const float*)d_in[11];
    const float* b2    = (const float*)d_in[12];
    const float* Wc    = (const float*)d_in[13];
    const float* bc    = (const float*)d_in[14];
    float* out = (float*)d_out;

    const size_t MPE = (size_t)MP * EQ;

    float* w = (float*)d_ws;
    float* bh    = w; w += MPE;
    float* res1  = w; w += MPE;
    float* logit = w; w += (size_t)BQ * CQ;
    unsigned short* qpk  = (unsigned short*)w;
    unsigned short* kpk  = qpk + QPK_TOT;
    unsigned short* vpk  = kpk + QPK_TOT;
    unsigned short* actb = vpk + VPK_TOT;           // packed activations
    unsigned short* ffh  = actb + MPE;              // packed FF hidden (MP x FQ)
    unsigned short* wbuf = ffh + (size_t)MP * FQ;

    const size_t WQKV = (size_t)EQ * EQ;
    unsigned short* WcvT = wbuf;                    // phase B overlays
    unsigned short* W1T  = wbuf + WQKV;
    unsigned short* W2T  = W1T + (size_t)EQ * FQ;

    copy_pad<<<BSQ, 256, 0, stream>>>(x, bh);

    for (int l = 0; l < LQ; ++l) {
        tconv_qkv3<<<dim3(12, 1, 3 * HQ), 256, 0, stream>>>(
            Wq + (size_t)l * HQ * EQ * DHQ, Wk + (size_t)l * HQ * EQ * DHQ,
            Wv + (size_t)l * HQ * EQ * DHQ, wbuf);

        ln_kernel<<<MP, 256, 0, stream>>>(bh, ln1w + l * EQ, ln1b + l * EQ, (__hip_bfloat16*)actb);

        mgemm_pk<EPI_QKV, 24, 4><<<8 * 7 * 18, 256, 0, stream>>>(
            actb, wbuf, qpk, (const float*)kpk, (const float*)vpk, QKV3, 18);

        tconv_pk<<<dim3(12, 12, 1), 256, 0, stream>>>(Wconv + (size_t)l * EQ * EQ, WcvT, EQ, 24, 0, 0);
        tconv_pk<<<dim3(12, 32, 1), 256, 0, stream>>>(W1 + (size_t)l * EQ * FQ, W1T, FQ, 24, 0, 0);
        tconv_pk<<<dim3(32, 12, 1), 256, 0, stream>>>(W2 + (size_t)l * FQ * EQ, W2T, EQ, 64, 0, 0);

        attn_fused<<<dim3(BQ * HQ, 7), 128, 0, stream>>>(qpk, kpk, vpk, actb);

        mgemm_pk<EPI_RES, 24, 2><<<8 * 13 * 6, 256, 0, stream>>>(
            actb, WcvT, res1, nullptr, bh, EQ, 6);

        ln_kernel<<<MP, 256, 0, stream>>>(res1, ln2w + l * EQ, ln2b + l * EQ, (__hip_bfloat16*)actb);

        mgemm_pk<EPI_BIAS_GELU, 24, 4><<<8 * 7 * 16, 256, 0, stream>>>(
            actb, W1T, ffh, b1 + l * FQ, nullptr, FQ, 16);
        mgemm_pk<EPI_BIAS_RES, 64, 2><<<8 * 13 * 6, 256, 0, stream>>>(
            ffh, W2T, bh, b2 + l * EQ, res1, EQ, 6);
    }
    logits_kernel<<<dim3(32, BQ), 256, 0, stream>>>(bh, Wc, bc, logit);
    smax_kernel<<<BQ, 256, 0, stream>>>(logit, out);
}

// Round 6
// 710.471 us; speedup vs baseline: 1.5500x; 1.1172x over previous
//
#include <hip/hip_runtime.h>
#include <hip/hip_bf16.h>
#include <math.h>

#define BQ 32
#define SQ 197
#define EQ 768
#define HQ 12
#define DHQ 64
#define FQ 2048
#define LQ 4
#define CQ 1000
#define BSQ (BQ*SQ)     // 6304
#define SP 208          // padded rows per batch (13 * 16)
#define S16 13          // 16-row tiles per batch
#define MP (BQ*SP)      // 6656 padded total rows
#define QKV3 2304
#define KTP 7           // t-chunks of 32 (224) for P / V
#define LN_EPS 1e-5f

typedef __bf16 bf16x8 __attribute__((ext_vector_type(8)));
typedef float f32x4 __attribute__((ext_vector_type(4)));
typedef unsigned short u16x8 __attribute__((ext_vector_type(8)));

typedef const __attribute__((address_space(1))) unsigned int* gas_t;
typedef __attribute__((address_space(3))) unsigned int* las_t;

__device__ __forceinline__ __hip_bfloat16 tobf(float f) { return __float2bfloat16(f); }

// Packed fragment layout: chunk of 8 bf16 for (row-tile rt, k-tile kt, lane):
//   buf[pk(rt,KT,kt,lane)+e] <-> A[rt*16+(lane&15)][kt*32+(lane>>4)*8+e]
__device__ __forceinline__ size_t pk(int rt, int KT, int kt, int lane) {
    return (((size_t)rt * KT + kt) * 64 + (size_t)lane) * 8;
}

// sizes (elems)
#define QPK_SLAB (S16*2*512)            // per (b,h): 13 rt x 2 kt x 512
#define QPK_TOT  ((size_t)BQ*HQ*QPK_SLAB + 4096)
#define VPK_SLAB (4*KTP*512)            // per (b,h): 4 dt x 7 tt x 512
#define VPK_TOT  ((size_t)BQ*HQ*VPK_SLAB + 4096)
// per-layer packed weight slab: WqT,WkT,WvT,WcvT (4x E*E) + W1T (E*F) + W2T (F*E)
#define LWSLAB (4*(size_t)EQ*EQ + 2*(size_t)EQ*FQ)

template<int N>
__device__ __forceinline__ void waitvm() {
    asm volatile("s_waitcnt vmcnt(%0)" :: "n"(N) : "memory");
}
__device__ __forceinline__ void barx() {
    asm volatile("" ::: "memory");
    __builtin_amdgcn_s_barrier();
    asm volatile("" ::: "memory");
}
// wave-local LDS fence: cross-LANE LDS RAW within one wave needs an explicit
// lgkmcnt drain + sched_barrier (rule #18).
__device__ __forceinline__ void lds_fence() {
    asm volatile("s_waitcnt lgkmcnt(0)" ::: "memory");
    __builtin_amdgcn_sched_barrier(0);
}

// fast exact-form GELU: erf via A&S 7.1.26 (|erf err| < 1.5e-7)
__device__ __forceinline__ float gelu_f(float v) {
    float ax = fabsf(v) * 0.70710678118654752f;
    float t  = __builtin_amdgcn_rcpf(1.0f + 0.3275911f * ax);
    float p  = ((((1.061405429f * t - 1.453152027f) * t + 1.421413741f) * t
               - 0.284496736f) * t + 0.254829592f) * t;
    float e  = __expf(-ax * ax);
    float er = 1.0f - p * e;                 // erf(|x|)
    return v * (0.5f * (1.0f + copysignf(er, v)));
}

// ---------------- copy x into padded residual stream (zero pad rows) --------
__global__ __launch_bounds__(256) void copy_pad(const float* __restrict__ x,
    float* __restrict__ bh)
{
    int r = blockIdx.x;                  // 0..MP-1
    int b = r / SP, s = r - b * SP;
    float* dst = bh + (size_t)r * EQ;
    int t = threadIdx.x;
    if (s < SQ) {
        const float* src = x + ((size_t)b * SQ + s) * EQ;
        dst[t]       = src[t];
        dst[t + 256] = src[t + 256];
        dst[t + 512] = src[t + 512];
    } else {
        dst[t] = 0.f; dst[t + 256] = 0.f; dst[t + 512] = 0.f;
    }
}

// ---------------- transpose + convert + PACK weights ------------------------
__device__ __forceinline__ void tconv_body(const float* __restrict__ ip,
    unsigned short* __restrict__ out, int C, int KT, int ntb_base, int r0, int c0)
{
    __shared__ float tile[64][65];
    int t = threadIdx.x;
    int tc = t & 63, tr = t >> 6;
    #pragma unroll
    for (int p = 0; p < 16; ++p) {
        int r = p * 4 + tr;
        tile[r][tc] = ip[(size_t)(r0 + r) * C + c0 + tc];
    }
    __syncthreads();
    int ntb = ntb_base + (c0 >> 4);
    int ktb = r0 >> 5;
    #pragma unroll
    for (int p = 0; p < 2; ++p) {
        int cc = p * 256 + t;
        int lane = cc & 63, grp = cc >> 6;
        int ktl = grp & 1, ntl = grp >> 1;
        int er = ktl * 32 + (lane >> 4) * 8;
        int dc = ntl * 16 + (lane & 15);
        u16x8 v;
        #pragma unroll
        for (int e = 0; e < 8; ++e) {
            __hip_bfloat16 h = tobf(tile[er + e][dc]);
            v[e] = *(unsigned short*)&h;
        }
        *(u16x8*)(out + pk(ntb + ntl, KT, ktb + ktl, lane)) = v;
    }
}

// ALL weight repacks for ALL 4 layers in ONE launch (5376 blocks, full fill).
// Per layer: 432 blocks qkv (12 x, 36 z) + 144 Wconv + 384 W1 + 384 W2 = 1344.
__global__ __launch_bounds__(256) void tconv_all(
    const float* __restrict__ Wq, const float* __restrict__ Wk,
    const float* __restrict__ Wv, const float* __restrict__ Wcv,
    const float* __restrict__ W1, const float* __restrict__ W2,
    unsigned short* __restrict__ wAll)
{
    int id = blockIdx.x;
    const int l = id / 1344; id -= l * 1344;
    unsigned short* wl = wAll + (size_t)l * LWSLAB;
    const float* src; unsigned short* dst;
    int C, KT, ntb, r0, c0;
    if (id < 432) {                      // Wq/Wk/Wv per head
        int x = id % 12, z = id / 12;    // z 0..35
        int which = z / 12, zz = z - which * 12;
        const float* s0 = (which == 0) ? Wq : (which == 1) ? Wk : Wv;
        src = s0 + ((size_t)l * HQ + zz) * EQ * DHQ;
        dst = wl + (size_t)which * EQ * EQ;
        C = DHQ; KT = 24; ntb = zz * 4; r0 = x * 64; c0 = 0;
    } else if (id < 576) {               // Wconv
        int t = id - 432;
        src = Wcv + (size_t)l * EQ * EQ;
        dst = wl + 3 * (size_t)EQ * EQ;
        C = EQ; KT = 24; ntb = 0; r0 = (t % 12) * 64; c0 = (t / 12) * 64;
    } else if (id < 960) {               // W1
        int t = id - 576;
        src = W1 + (size_t)l * EQ * FQ;
        dst = wl + 4 * (size_t)EQ * EQ;
        C = FQ; KT = 24; ntb = 0; r0 = (t % 12) * 64; c0 = (t / 12) * 64;
    } else {                             // W2 (K=2048 -> KT=64)
        int t = id - 960;
        src = W2 + (size_t)l * FQ * EQ;
        dst = wl + 4 * (size_t)EQ * EQ + (size_t)EQ * FQ;
        C = EQ; KT = 64; ntb = 0; r0 = (t % 32) * 64; c0 = (t / 32) * 64;
    }
    tconv_body(src, dst, C, KT, ntb, r0, c0);
}

// ---------------- LayerNorm: wave-per-row, no LDS, no barriers --------------
// 4 waves/block, one row each. Lane L owns chunk c=L (k=8L..8L+8) and, for
// L<32, chunk 64+L (k=512+8L..). Two-pass mean/var via full-wave shfl_xor.
// Packed store: chunk c -> pk(row>>4, 24, c>>2, (c&3)*16 + (row&15)).
__global__ __launch_bounds__(256) void ln_kernel(const float* __restrict__ in,
    const float* __restrict__ w, const float* __restrict__ b,
    unsigned short* __restrict__ out)
{
    const int wv = threadIdx.x >> 6, L = threadIdx.x & 63;
    const int row = blockIdx.x * 4 + wv;
    const float* x = in + (size_t)row * EQ;
    float4 a0 = *(const float4*)(x + 8 * L);
    float4 a1 = *(const float4*)(x + 8 * L + 4);
    float4 a2 = make_float4(0.f, 0.f, 0.f, 0.f), a3 = a2;
    const bool two = (L < 32);
    if (two) {
        a2 = *(const float4*)(x + 512 + 8 * L);
        a3 = *(const float4*)(x + 512 + 8 * L + 4);
    }
    float s = a0.x + a0.y + a0.z + a0.w + a1.x + a1.y + a1.z + a1.w
            + a2.x + a2.y + a2.z + a2.w + a3.x + a3.y + a3.z + a3.w;
    #pragma unroll
    for (int d = 1; d < 64; d <<= 1) s += __shfl_xor(s, d);
    const float mu = s * (1.0f / EQ);
    float q = (a0.x-mu)*(a0.x-mu) + (a0.y-mu)*(a0.y-mu) + (a0.z-mu)*(a0.z-mu) + (a0.w-mu)*(a0.w-mu)
            + (a1.x-mu)*(a1.x-mu) + (a1.y-mu)*(a1.y-mu) + (a1.z-mu)*(a1.z-mu) + (a1.w-mu)*(a1.w-mu);
    if (two)
        q += (a2.x-mu)*(a2.x-mu) + (a2.y-mu)*(a2.y-mu) + (a2.z-mu)*(a2.z-mu) + (a2.w-mu)*(a2.w-mu)
           + (a3.x-mu)*(a3.x-mu) + (a3.y-mu)*(a3.y-mu) + (a3.z-mu)*(a3.z-mu) + (a3.w-mu)*(a3.w-mu);
    #pragma unroll
    for (int d = 1; d < 64; d <<= 1) q += __shfl_xor(q, d);
    const float rs = rsqrtf(q * (1.0f / EQ) + LN_EPS);

    const int rt = row >> 4, rsl = row & 15;
    auto store_chunk = [&](int c, float4 v0, float4 v1) {
        int kt = c >> 2, c2 = c & 3;
        int lane2 = (c2 << 4) + rsl;
        int k0 = c << 3;
        float4 w0 = *(const float4*)(w + k0), w1 = *(const float4*)(w + k0 + 4);
        float4 g0 = *(const float4*)(b + k0), g1 = *(const float4*)(b + k0 + 4);
        float va[8] = {v0.x, v0.y, v0.z, v0.w, v1.x, v1.y, v1.z, v1.w};
        float wa[8] = {w0.x, w0.y, w0.z, w0.w, w1.x, w1.y, w1.z, w1.w};
        float ba[8] = {g0.x, g0.y, g0.z, g0.w, g1.x, g1.y, g1.z, g1.w};
        u16x8 o;
        #pragma unroll
        for (int e = 0; e < 8; ++e) {
            __hip_bfloat16 h = tobf((va[e] - mu) * rs * wa[e] + ba[e]);
            o[e] = *(unsigned short*)&h;
        }
        *(u16x8*)(out + pk(rt, 24, kt, lane2)) = o;
    };
    store_chunk(L, a0, a1);
    if (two) store_chunk(64 + L, a2, a3);
}

// ---------------- LDS-staged MFMA K-loop (T3/T4) ----------------------------
template<int KT, int RT>
__device__ __forceinline__ void kloop_staged(
    const unsigned short* __restrict__ Apk,
    const unsigned short* __restrict__ Bpk,
    int rtb, int ntb, int tid, unsigned short* sm, f32x4 (&acc)[RT][4])
{
    static_assert(KT >= 3, "need >=3 k-tiles");
    constexpr int AC  = RT * 2;      // A chunks per k-tile (1KB each)
    constexpr int NCH = AC + 8;      // + 8 B chunks
    constexpr int CPW = NCH / 4;     // stage calls per wave per k-tile
    const int lane = tid & 63, w = tid >> 6;
    const int wr = w >> 1, wc = w & 1;
    const int cbase = w * CPW;

    const unsigned short* sp[CPW];
    #pragma unroll
    for (int q = 0; q < CPW; ++q) {
        int c = cbase + q;
        sp[q] = (c < AC) ? Apk + pk(rtb + c, KT, 0, lane)
                         : Bpk + pk(ntb + (c - AC), KT, 0, lane);
    }
    unsigned short* bufs0 = sm;
    unsigned short* bufs1 = sm + NCH * 512;
    unsigned short* bufs2 = sm + 2 * NCH * 512;

    auto stagef = [&](unsigned short* dst) {
        #pragma unroll
        for (int q = 0; q < CPW; ++q) {
            __builtin_amdgcn_global_load_lds(
                (gas_t)sp[q], (las_t)(dst + (cbase + q) * 512), 16, 0, 0);
            sp[q] += 512;
        }
    };
    auto frags = [&](const unsigned short* cur, bf16x8 (&af)[RT], bf16x8 (&bb)[4]) {
        #pragma unroll
        for (int i = 0; i < RT; ++i)
            af[i] = *(const bf16x8*)(cur + (wr * RT + i) * 512 + lane * 8);
        #pragma unroll
        for (int j = 0; j < 4; ++j)
            bb[j] = *(const bf16x8*)(cur + (AC + wc * 4 + j) * 512 + lane * 8);
    };
    auto mf = [&](bf16x8 (&af)[RT], bf16x8 (&bb)[4]) {
        #pragma unroll
        for (int i = 0; i < RT; ++i)
            #pragma unroll
            for (int j = 0; j < 4; ++j)
                acc[i][j] = __builtin_amdgcn_mfma_f32_16x16x32_bf16(af[i], bb[j], acc[i][j], 0, 0, 0);
    };

    stagef(bufs0);                    // tile 0
    stagef(bufs1);                    // tile 1
    unsigned short *cur = bufs0, *nxt = bufs1, *nx2 = bufs2;

    #pragma unroll 1
    for (int kt = 0; kt < KT - 2; ++kt) {
        waitvm<CPW>();                // stage(kt) done; stage(kt+1) in flight
        barx();
        bf16x8 af[RT], bb[4];
        frags(cur, af, bb);
        stagef(nx2);                  // tile kt+2
        mf(af, bb);
        unsigned short* t_ = cur; cur = nxt; nxt = nx2; nx2 = t_;
    }
    {   // kt = KT-2
        waitvm<CPW>();
        barx();
        bf16x8 af[RT], bb[4];
        frags(cur, af, bb);
        mf(af, bb);
        cur = nxt;
    }
    {   // kt = KT-1
        waitvm<0>();
        barx();
        bf16x8 af[RT], bb[4];
        frags(cur, af, bb);
        mf(af, bb);
    }
}

// ---------------- unified packed MFMA GEMM (staged) -------------------------
enum { EPI_NONE = 0, EPI_RES = 1, EPI_BIAS_GELU = 2, EPI_BIAS_RES = 3, EPI_QKV = 4 };

template<int EPI, int KT, int RT>
__global__ __launch_bounds__(256, 3) void mgemm_pk(
    const unsigned short* __restrict__ Apk, const unsigned short* __restrict__ Bpk,
    void* __restrict__ Cm, const float* __restrict__ bias,
    const float* __restrict__ res, int N, int nNT)
{
    constexpr int NCH = RT * 2 + 8;
    __shared__ __align__(16) unsigned short smem[(3 * NCH * 1024) / 2];

    const int nRowT = (RT == 4) ? 52 : 104;        // MP/(RT*32)
    const int g = blockIdx.x & 7;
    const int sIdx = blockIdx.x >> 3;
    const int b0 = (nRowT * g) >> 3, b1 = (nRowT * (g + 1)) >> 3;
    const int colT = sIdx % nNT, rloc = sIdx / nNT;
    if (b0 + rloc >= b1) return;
    const int row0 = (b0 + rloc) * (RT * 32), col0 = colT << 7;

    const int tid = threadIdx.x;
    const int lane = tid & 63;
    const int w = tid >> 6;
    const int wr = w >> 1, wc = w & 1;
    const int l15 = lane & 15, quad = lane >> 4;

    f32x4 acc[RT][4] = {};
    kloop_staged<KT, RT>(Apk, Bpk, row0 >> 4, col0 >> 4, tid, smem, acc);

    if constexpr (EPI == EPI_BIAS_GELU) {
        __syncthreads();              // smem reused as Cs below
        auto Cs = (unsigned short (*)[136])smem;
        #pragma unroll
        for (int j = 0; j < 4; ++j) {
            float bv = bias[col0 + wc * 64 + j * 16 + l15];
            #pragma unroll
            for (int i = 0; i < RT; ++i)
                #pragma unroll
                for (int rg = 0; rg < 4; ++rg) {
                    float v = gelu_f(acc[i][j][rg] + bv);
                    __hip_bfloat16 h = tobf(v);
                    Cs[wr * 64 + i * 16 + quad * 4 + rg][wc * 64 + j * 16 + l15] =
                        *(unsigned short*)&h;
                }
        }
        __syncthreads();
        const int KT2 = N >> 5;
        #pragma unroll
        for (int p = 0; p < 8; ++p) {
            int cc = p * 256 + tid;
            int ln2 = cc & 63, grp = cc >> 6;
            int ktl = grp & 3, rtl = grp >> 2;
            int rowl = rtl * 16 + (ln2 & 15);
            u16x8 v;
            #pragma unroll
            for (int e = 0; e < 8; ++e)
                v[e] = Cs[rowl][ktl * 32 + (ln2 >> 4) * 8 + e];
            *(u16x8*)((unsigned short*)Cm + pk((row0 >> 4) + rtl, KT2, (col0 >> 5) + ktl, ln2)) = v;
        }
    } else if constexpr (EPI == EPI_QKV) {
        unsigned short* qpk = (unsigned short*)Cm;
        unsigned short* kpk = (unsigned short*)(void*)bias;
        unsigned short* vpk = (unsigned short*)(void*)res;
        __syncthreads();              // smem reused as Cs below
        auto Cs = (unsigned short (*)[136])smem;
        #pragma unroll
        for (int j = 0; j < 4; ++j)
            #pragma unroll
            for (int i = 0; i < 4; ++i)
                #pragma unroll
                for (int rg = 0; rg < 4; ++rg) {
                    __hip_bfloat16 h = tobf(acc[i][j][rg]);
                    Cs[wr * 64 + i * 16 + quad * 4 + rg][wc * 64 + j * 16 + l15] =
                        *(unsigned short*)&h;
                }
        __syncthreads();

        const int treg = col0 >> 7;   // 0..5 q, 6..11 k, 12..17 v
        if (treg < 12) {
            unsigned short* dst = (treg < 6) ? qpk : kpk;
            const int h0 = ((col0 % 768) >> 6);
            #pragma unroll
            for (int p = 0; p < 8; ++p) {
                int cc = p * 256 + tid;
                int ln2 = cc & 63, grp = cc >> 6;
                int hl = grp & 1, kt = (grp >> 1) & 1, rtl = grp >> 2;
                int row16 = (row0 >> 4) + rtl;
                int bb = row16 / S16;
                int s16 = row16 - bb * S16;
                int h = h0 + hl;
                u16x8 v;
                #pragma unroll
                for (int e = 0; e < 8; ++e)
                    v[e] = Cs[rtl * 16 + (ln2 & 15)][hl * 64 + kt * 32 + (ln2 >> 4) * 8 + e];
                *(u16x8*)(dst + ((((size_t)(bb * HQ + h) * S16 + s16) * 2 + kt) << 9) + ln2 * 8) = v;
            }
        } else {
            const int h0 = (col0 - 1536) >> 6;     // block covers heads h0, h0+1
            #pragma unroll
            for (int p = 0; p < 8; ++p) {
                int cc = p * 256 + tid;
                int dloc = cc & 127;
                int g8 = cc >> 7;
                int gr = row0 + g8 * 8;
                int bb = gr / SP;
                int tl = gr - bb * SP;
                int tt = tl >> 5;
                int tsub = (tl >> 3) & 3;
                int h = h0 + (dloc >> 6);
                int dt = (dloc >> 4) & 3;
                int lane2 = tsub * 16 + (dloc & 15);
                u16x8 v;
                #pragma unroll
                for (int e = 0; e < 8; ++e)
                    v[e] = Cs[g8 * 8 + e][dloc];
                *(u16x8*)(vpk + (size_t)(bb * HQ + h) * VPK_SLAB + pk(dt, KTP, tt, lane2)) = v;
            }
        }
    } else {
        #pragma unroll
        for (int j = 0; j < 4; ++j) {
            int c = col0 + wc * 64 + j * 16 + l15;
            float bv = (EPI == EPI_BIAS_RES) ? bias[c] : 0.f;
            #pragma unroll
            for (int i = 0; i < RT; ++i)
                #pragma unroll
                for (int rg = 0; rg < 4; ++rg) {
                    int r = row0 + wr * (RT * 16) + i * 16 + quad * 4 + rg;
                    float v = acc[i][j][rg];
                    size_t idx = (size_t)r * N + c;
                    if (EPI == EPI_BIAS_RES) {
                        ((float*)Cm)[idx] = v + bv + res[idx];
                    } else if (EPI == EPI_RES) {
                        ((float*)Cm)[idx] = v + res[idx];
                    } else {
                        ((__hip_bfloat16*)Cm)[idx] = tobf(v);
                    }
                }
        }
    }
}

// ------------- FUSED attention: barrier-free, one wave per 16-row Q tile ----
__global__ __launch_bounds__(128, 4) void attn_fused(
    const unsigned short* __restrict__ qpk, const unsigned short* __restrict__ kpk,
    const unsigned short* __restrict__ vpk, unsigned short* __restrict__ opk)
{
    __shared__ unsigned short Ps[2][16][240];   // P, col XOR-swizzled by row bit3
    __shared__ unsigned short Cs[2][16][72];    // output transpose scratch
    const int bh = blockIdx.x;
    const int b = bh / HQ, h = bh - b * HQ;
    const int tid = threadIdx.x;
    const int w = tid >> 6, lane = tid & 63;
    const int l15 = lane & 15, quad = lane >> 4;
    const int rt = blockIdx.y * 2 + w;          // 0..13; 13 is empty
    if (rt >= S16) return;

    const unsigned short* qs = qpk + (size_t)bh * QPK_SLAB;
    const unsigned short* ks = kpk + (size_t)bh * QPK_SLAB;
    const unsigned short* vs = vpk + (size_t)bh * VPK_SLAB;

    // Q fragments (2 k-tiles)
    bf16x8 af0 = *(const bf16x8*)(qs + ((rt * 2 + 0) << 9) + lane * 8);
    bf16x8 af1 = *(const bf16x8*)(qs + ((rt * 2 + 1) << 9) + lane * 8);

    // QK^T over all 13 col-tiles, 1-deep K prefetch
    f32x4 acc[13] = {};
    bf16x8 kc0 = *(const bf16x8*)(ks + (0 << 9) + lane * 8);
    bf16x8 kc1 = *(const bf16x8*)(ks + (1 << 9) + lane * 8);
    #pragma unroll
    for (int j = 0; j < 13; ++j) {
        bf16x8 kn0, kn1;
        if (j + 1 < 13) {
            kn0 = *(const bf16x8*)(ks + (((j + 1) * 2 + 0) << 9) + lane * 8);
            kn1 = *(const bf16x8*)(ks + (((j + 1) * 2 + 1) << 9) + lane * 8);
        }
        __builtin_amdgcn_s_setprio(1);
        acc[j] = __builtin_amdgcn_mfma_f32_16x16x32_bf16(af0, kc0, acc[j], 0, 0, 0);
        acc[j] = __builtin_amdgcn_mfma_f32_16x16x32_bf16(af1, kc1, acc[j], 0, 0, 0);
        __builtin_amdgcn_s_setprio(0);
        kc0 = kn0; kc1 = kn1;
    }

    // prefetch V k-tile 0 (lands during softmax)
    bf16x8 vb[4];
    #pragma unroll
    for (int d = 0; d < 4; ++d)
        vb[d] = *(const bf16x8*)(vs + pk(d, KTP, 0, lane));

    // in-wave softmax: rows quad*4+rg live in 16 lanes (same quad, all l15)
    const float scale = 0.07124704998790965f;  // 1/sqrt(197)
    const int xr = (quad & 2) << 3;            // row-bit3 col swizzle
    const unsigned short zbf = 0;              // bf16 +0.0
    float inv[4];
    #pragma unroll
    for (int rg = 0; rg < 4; ++rg) {
        float y[13];
        float m = -1e30f;
        #pragma unroll
        for (int j = 0; j < 13; ++j) {
            float v = acc[j][rg] * scale;
            if (j == 12) v = (l15 < 5) ? v : -1e30f;   // cols 197..207 masked
            y[j] = v;
            m = fmaxf(m, v);
        }
        #pragma unroll
        for (int d = 1; d < 16; d <<= 1) m = fmaxf(m, __shfl_xor(m, d));
        float s = 0.f;
        #pragma unroll
        for (int j = 0; j < 13; ++j) {
            float e = __expf(y[j] - m);        // e in [0,1] -> bf16-safe
            s += e;
            __hip_bfloat16 hv = tobf(e);
            Ps[w][quad * 4 + rg][(j * 16 + l15) ^ xr] = *(unsigned short*)&hv;
        }
        // zero-fill pad tile j=13 (t=208..223) — PV reads these columns
        Ps[w][quad * 4 + rg][(208 + l15) ^ xr] = zbf;
        #pragma unroll
        for (int d = 1; d < 16; d <<= 1) s += __shfl_xor(s, d);
        inv[rg] = 1.0f / s;                    // applied to av post-PV
    }
    lds_fence();                               // P visible to all lanes of wave

    // P @ V : A-frag from wave-private Ps, B-frags from vpk (1-deep prefetch)
    f32x4 av[4] = {};
    #pragma unroll
    for (int kk = 0; kk < KTP; ++kk) {
        bf16x8 vn[4];
        if (kk + 1 < KTP) {
            #pragma unroll
            for (int d = 0; d < 4; ++d)
                vn[d] = *(const bf16x8*)(vs + pk(d, KTP, kk + 1, lane));
        }
        int col = (kk * 32 + quad * 8) ^ ((l15 & 8) << 1);
        bf16x8 pf = *(const bf16x8*)&Ps[w][l15][col];
        __builtin_amdgcn_s_setprio(1);
        #pragma unroll
        for (int d = 0; d < 4; ++d)
            av[d] = __builtin_amdgcn_mfma_f32_16x16x32_bf16(pf, vb[d], av[d], 0, 0, 0);
        __builtin_amdgcn_s_setprio(0);
        #pragma unroll
        for (int d = 0; d < 4; ++d) vb[d] = vn[d];
    }

    // normalize + transpose via wave-private Cs -> packed opk (A-frag layout)
    #pragma unroll
    for (int d = 0; d < 4; ++d)
        #pragma unroll
        for (int rg = 0; rg < 4; ++rg) {
            __hip_bfloat16 hv = tobf(av[d][rg] * inv[rg]);
            Cs[w][quad * 4 + rg][d * 16 + l15] = *(unsigned short*)&hv;
        }
    lds_fence();

    const int rtg = b * S16 + rt;
    #pragma unroll
    for (int ktl = 0; ktl < 2; ++ktl) {
        u16x8 v;
        #pragma unroll
        for (int e = 0; e < 8; ++e)
            v[e] = Cs[w][l15][ktl * 32 + quad * 8 + e];
        *(u16x8*)(opk + pk(rtg, 24, h * 2 + ktl, lane)) = v;
    }
}

// ---------------- classifier: split-K logits + softmax ----------------------
__global__ __launch_bounds__(256) void logits_kernel(
    const float* __restrict__ hbuf, const float* __restrict__ Wc,
    const float* __restrict__ bc, float* __restrict__ logits)
{
    __shared__ __align__(16) float hs[768];
    __shared__ float red[256];
    int b = blockIdx.y;
    int tid = threadIdx.x;
    const float* hr = hbuf + (size_t)b * SP * EQ;   // s=0 row
    for (int p = tid; p < 192; p += 256)
        *(float4*)&hs[p << 2] = *(const float4*)(hr + (p << 2));
    __syncthreads();
    int cl = tid & 31, ks = tid >> 5;
    int c = blockIdx.x * 32 + cl;
    int cs = (c < CQ) ? c : 0;
    float s = 0.f;
    int e0 = ks * 96;
    #pragma unroll 8
    for (int e = 0; e < 96; ++e)
        s = fmaf(hs[e0 + e], Wc[(size_t)(e0 + e) * CQ + cs], s);
    red[tid] = s;
    __syncthreads();
    for (int off = 128; off >= 32; off >>= 1) {
        if (tid < off) red[tid] += red[tid + off];
        __syncthreads();
    }
    if (tid < 32 && c < CQ)
        logits[(size_t)b * CQ + c] = red[tid] + bc[c];
}

__global__ __launch_bounds__(256) void smax_kernel(
    const float* __restrict__ logits, float* __restrict__ out)
{
    __shared__ float red[256];
    int b = blockIdx.x;
    int t = threadIdx.x;
    const float* lp = logits + (size_t)b * CQ;
    float lg[4];
    #pragma unroll
    for (int j = 0; j < 4; ++j) {
        int c = t + j * 256;
        lg[j] = (c < CQ) ? lp[c] : -1e30f;
    }
    float m = fmaxf(fmaxf(lg[0], lg[1]), fmaxf(lg[2], lg[3]));
    red[t] = m;
    __syncthreads();
    for (int off = 128; off; off >>= 1) {
        if (t < off) red[t] = fmaxf(red[t], red[t + off]);
        __syncthreads();
    }
    m = red[0];
    __syncthreads();
    float ex[4], s = 0.f;
    #pragma unroll
    for (int j = 0; j < 4; ++j) {
        ex[j] = (t + j * 256 < CQ) ? __expf(lg[j] - m) : 0.f;
        s += ex[j];
    }
    red[t] = s;
    __syncthreads();
    for (int off = 128; off; off >>= 1) {
        if (t < off) red[t] += red[t + off];
        __syncthreads();
    }
    float inv = 1.0f / red[0];
    #pragma unroll
    for (int j = 0; j < 4; ++j)
        if (t + j * 256 < CQ) out[(size_t)b * CQ + t + j * 256] = ex[j] * inv;
}

extern "C" void kernel_launch(void* const* d_in, const int* in_sizes, int n_in,
                              void* d_out, int out_size, void* d_ws, size_t ws_size,
                              hipStream_t stream)
{
    const float* x     = (const float*)d_in[0];
    const float* Wk    = (const float*)d_in[1];
    const float* Wq    = (const float*)d_in[2];
    const float* Wv    = (const float*)d_in[3];
    const float* Wconv = (const float*)d_in[4];
    const float* ln1w  = (const float*)d_in[5];
    const float* ln1b  = (const float*)d_in[6];
    const float* ln2w  = (const float*)d_in[7];
    const float* ln2b  = (const float*)d_in[8];
    const float* W1    = (const float*)d_in[9];
    const float* b1    = (const float*)d_in[10];
    const float* W2    = (const float*)d_in[11];
    const float* b2    = (const float*)d_in[12];
    const float* Wc    = (const float*)d_in[13];
    const float* bc    = (const float*)d_in[14];
    float* out = (float*)d_out;

    const size_t MPE = (size_t)MP * EQ;

    float* w = (float*)d_ws;
    float* bh    = w; w += MPE;
    float* res1  = w; w += MPE;
    float* logit = w; w += (size_t)BQ * CQ;
    unsigned short* qpk  = (unsigned short*)w;
    unsigned short* kpk  = qpk + QPK_TOT;
    unsigned short* vpk  = kpk + QPK_TOT;
    unsigned short* actb = vpk + VPK_TOT;           // packed activations
    unsigned short* ffh  = actb + MPE;              // packed FF hidden (MP x FQ)
    unsigned short* wAll = ffh + (size_t)MP * FQ;   // 4 layers x LWSLAB packed W

    copy_pad<<<MP, 256, 0, stream>>>(x, bh);
    tconv_all<<<4 * 1344, 256, 0, stream>>>(Wq, Wk, Wv, Wconv, W1, W2, wAll);

    for (int l = 0; l < LQ; ++l) {
        unsigned short* wl   = wAll + (size_t)l * LWSLAB;
        unsigned short* WcvT = wl + 3 * (size_t)EQ * EQ;
        unsigned short* W1T  = wl + 4 * (size_t)EQ * EQ;
        unsigned short* W2T  = W1T + (size_t)EQ * FQ;

        ln_kernel<<<MP / 4, 256, 0, stream>>>(bh, ln1w + l * EQ, ln1b + l * EQ, actb);

        mgemm_pk<EPI_QKV, 24, 4><<<8 * 7 * 18, 256, 0, stream>>>(
            actb, wl, qpk, (const float*)kpk, (const float*)vpk, QKV3, 18);

        attn_fused<<<dim3(BQ * HQ, 7), 128, 0, stream>>>(qpk, kpk, vpk, actb);

        mgemm_pk<EPI_RES, 24, 2><<<8 * 13 * 6, 256, 0, stream>>>(
            actb, WcvT, res1, nullptr, bh, EQ, 6);

        ln_kernel<<<MP / 4, 256, 0, stream>>>(res1, ln2w + l * EQ, ln2b + l * EQ, actb);

        mgemm_pk<EPI_BIAS_GELU, 24, 4><<<8 * 7 * 16, 256, 0, stream>>>(
            actb, W1T, ffh, b1 + l * FQ, nullptr, FQ, 16);
        mgemm_pk<EPI_BIAS_RES, 64, 2><<<8 * 13 * 6, 256, 0, stream>>>(
            ffh, W2T, bh, b2 + l * EQ, res1, EQ, 6);
    }
    logits_kernel<<<dim3(32, BQ), 256, 0, stream>>>(bh, Wc, bc, logit);
    smax_kernel<<<BQ, 256, 0, stream>>>(logit, out);
}